// Round 1
// baseline (106.662 us; speedup 1.0000x reference)
//
#include <hip/hip_runtime.h>
#include <hip/hip_fp16.h>
#include <math.h>

#define N      512
#define DIMC   128
#define HEADS  4
#define DH     32
#define INDC   5
#define SCALE  0.1767766952966369f   // 32^-0.5

// Virtual output rows of the fused pre-GEMM: all are (row_weights) @ x
//   rows [0,384)   : qkv   (q rows 0..127, k 128..255, v 256..383)
//   rows [384,404) : Aq[(h*5+c)]  composite weight  Wq_rows . W_ind_k
//   rows [404,424) : Ak[(h*5+c)]  composite weight  Wk_rows . W_ind_q
// rows are stored FP16 (halves attn's L2-side K/V traffic; error << threshold)
#define QKV_ROWS 384
#define AQ_BASE  384
#define AK_BASE  404
#define TOT_ROWS 424
#define NROW_BLK (TOT_ROWS / 4)   // 106

// ws layout: [rows fp16: TOT_ROWS*N halves][MhS 64 f32][w_outT 16384 f32]
#define MHS_F    (TOT_ROWS * N / 2)      // float offset after fp16 rows
#define WOUTT_F  (MHS_F + 64)

// ---------------- Kernel 1: fused pre-GEMM + MhS + w_out transpose ----------------
__global__ __launch_bounds__(256) void pre_kernel(const float* __restrict__ w_qkv,
                                                  const float* __restrict__ w_ind,
                                                  const float* __restrict__ x,
                                                  const float* __restrict__ w_out,
                                                  float* __restrict__ ws) {
    const int bx = blockIdx.x;
    const int t  = threadIdx.x;
    __half* rows  = (__half*)ws;
    float* MhS    = ws + MHS_F;
    float* w_outT = ws + WOUTT_F;

    if (bx == NROW_BLK) {
        if (blockIdx.y != 0) return;
        // --- M[h,c,cc] = sum_d w_ind_q[h,d,c] * w_ind_k[h,d,cc], then symmetrize ---
        __shared__ float mraw[HEADS * INDC * INDC];
        if (t < HEADS * INDC * INDC) {
            const int h = t / 25, c = (t / 5) % 5, cc = t % 5;
            float acc = 0.f;
            for (int d = 0; d < DH; ++d)
                acc = fmaf(w_ind[(h * DH + d) * INDC + c],
                           w_ind[(DIMC + h * DH + d) * INDC + cc], acc);
            mraw[t] = acc;
        }
        __syncthreads();
        if (t < 64) {
            const int h = t >> 4, idx = t & 15;
            const int PC[10]  = {0, 0, 0, 0, 1, 1, 1, 2, 2, 3};
            const int PCC[10] = {1, 2, 3, 4, 2, 3, 4, 3, 4, 4};
            float s = 0.f;
            if (idx < 5) {
                s = mraw[h * 25 + idx * 5 + idx];
            } else if (idx < 15) {
                const int c = PC[idx - 5], cc = PCC[idx - 5];
                s = mraw[h * 25 + c * 5 + cc] + mraw[h * 25 + cc * 5 + c];
            }
            MhS[h * 16 + idx] = s;
        }
        // --- transpose w_out (128x128) so the fused outproj reads coalesced ---
        for (int idx = t; idx < DIMC * DIMC; idx += 256) {
            const int o = idx >> 7, c = idx & 127;
            w_outT[c * DIMC + o] = w_out[idx];
        }
        return;
    }

    // --- 4 virtual rows per block, c-major float4 layout in LDS ---
    __shared__ float ws2[4 * DIMC];   // ws2[c*4 + r]
    const int o0 = bx * 4;
    for (int idx = t; idx < 4 * DIMC; idx += 256) {
        const int r = idx & 3, m = idx >> 2;
        const int row = o0 + r;
        float val;
        if (row < QKV_ROWS) {
            val = w_qkv[row * DIMC + m];
        } else if (row < AK_BASE) {              // Aq composite: q-rows . W_ind_k
            const int rr = row - AQ_BASE, h = rr / INDC, c = rr % INDC;
            float acc = 0.f;
            for (int d = 0; d < DH; ++d)
                acc = fmaf(w_qkv[(h * DH + d) * DIMC + m],
                           w_ind[(DIMC + h * DH + d) * INDC + c], acc);
            val = acc;
        } else {                                  // Ak composite: k-rows . W_ind_q
            const int rr = row - AK_BASE, h = rr / INDC, c = rr % INDC;
            float acc = 0.f;
            for (int d = 0; d < DH; ++d)
                acc = fmaf(w_qkv[(DIMC + h * DH + d) * DIMC + m],
                           w_ind[(h * DH + d) * INDC + c], acc);
            val = acc;
        }
        ws2[m * 4 + r] = val;
    }
    __syncthreads();

    const int i = blockIdx.y * 256 + t;   // i-split halves per-block x traffic
    float acc[4] = {0.f, 0.f, 0.f, 0.f};
#pragma unroll 8
    for (int c = 0; c < DIMC; ++c) {
        const float xv = x[c * N + i];
        const float4 wv = *(const float4*)(ws2 + c * 4);
        acc[0] = fmaf(wv.x, xv, acc[0]);
        acc[1] = fmaf(wv.y, xv, acc[1]);
        acc[2] = fmaf(wv.z, xv, acc[2]);
        acc[3] = fmaf(wv.w, xv, acc[3]);
    }
#pragma unroll
    for (int r = 0; r < 4; ++r) rows[(o0 + r) * N + i] = __float2half(acc[r]);
}

// -- Kernel 2: per-i mega kernel — sim(4h) + softmax + PV + outproj --
// ONE query column per block (grid = N = 512): 2+ blocks/CU resident so memory
// latency on K/V/ind loads is hidden by a co-resident block's compute.
__global__ __launch_bounds__(256) void attn_kernel(const float* __restrict__ ws,
                                                   const float* __restrict__ ind,
                                                   const float* __restrict__ b_out,
                                                   float* __restrict__ out) {
    const int i    = blockIdx.x;
    const int t    = threadIdx.x;
    const int lane = t & 63;
    const int wave = t >> 6;

    const __half* rows  = (const __half*)ws;
    const float* MhS    = ws + MHS_F;
    const float* w_outT = ws + WOUTT_F;

    const __half* q  = rows;
    const __half* Aq = rows + 3 * DIMC * N;

    __shared__ float qs[DIMC];
    __shared__ float aqs[HEADS * INDC];
    __shared__ float msS[HEADS * 16];
    __shared__ float ps[HEADS][N];          // 8 KB
    __shared__ float red[HEADS][DH][64];    // 32 KB
    __shared__ float red4[2][HEADS][4];
    __shared__ float attv[DIMC];
    __shared__ float outred[4][DIMC];       // 2 KB

    if (t < DIMC) {
        qs[t] = __half2float(q[t * N + i]);
    } else if (t < DIMC + HEADS * INDC) {
        const int r = t - DIMC;
        aqs[r] = __half2float(Aq[r * N + i]);
    } else if (t < DIMC + HEADS * INDC + 64) {
        const int r = t - DIMC - HEADS * INDC;
        msS[r] = MhS[r];
    }
    __syncthreads();

    // ---- phase 1: sim for all heads; thread t owns j-pair (2t,2t+1) ----
    float2 ic[INDC];
#pragma unroll
    for (int c = 0; c < INDC; ++c)
        ic[c] = ((const float2*)(ind + (c * N + i) * N))[t];

    // shared symmetric products: 5 squares + 10 cross (order matches PC/PCC)
    float2 prod[15];
#pragma unroll
    for (int c = 0; c < INDC; ++c)
        prod[c] = make_float2(ic[c].x * ic[c].x, ic[c].y * ic[c].y);
    {
        int p = 5;
#pragma unroll
        for (int c = 0; c < INDC; ++c)
#pragma unroll
            for (int cc = c + 1; cc < INDC; ++cc, ++p)
                prod[p] = make_float2(ic[c].x * ic[cc].x, ic[c].y * ic[cc].y);
    }

    const __half2* k2  = (const __half2*)(rows + DIMC * N);
    const __half2* Ak2 = (const __half2*)(rows + (3 * DIMC + HEADS * INDC) * N);
    float2 sim[HEADS];
#pragma unroll
    for (int h = 0; h < HEADS; ++h) {
        float2 qk = {0.f, 0.f};
#pragma unroll
        for (int d = 0; d < DH; ++d) {
            const float2 kv = __half22float2(k2[(h * DH + d) * 256 + t]);
            const float q0 = qs[h * DH + d];
            qk.x = fmaf(q0, kv.x, qk.x); qk.y = fmaf(q0, kv.y, qk.y);
        }
        float2 lin = {0.f, 0.f};
#pragma unroll
        for (int c = 0; c < INDC; ++c) {
            const float2 akv = __half22float2(Ak2[(h * INDC + c) * 256 + t]);
            const float a0 = aqs[h * INDC + c];
            lin.x = fmaf(a0 + akv.x, ic[c].x, lin.x);
            lin.y = fmaf(a0 + akv.y, ic[c].y, lin.y);
        }
        float2 qd = {0.f, 0.f};
#pragma unroll
        for (int p = 0; p < 15; ++p) {
            const float sv = msS[h * 16 + p];
            qd.x = fmaf(sv, prod[p].x, qd.x); qd.y = fmaf(sv, prod[p].y, qd.y);
        }
        sim[h].x = SCALE * (qk.x + lin.x + qd.x);
        sim[h].y = SCALE * (qk.y + lin.y + qd.y);
    }

    // ---- softmax per head over 512 ----
#pragma unroll
    for (int h = 0; h < HEADS; ++h) {
        float m = fmaxf(sim[h].x, sim[h].y);
#pragma unroll
        for (int off = 32; off; off >>= 1)
            m = fmaxf(m, __shfl_down(m, off, 64));
        if (lane == 0) red4[0][h][wave] = m;
    }
    __syncthreads();
    float2 e[HEADS];
#pragma unroll
    for (int h = 0; h < HEADS; ++h) {
        const float m = fmaxf(fmaxf(red4[0][h][0], red4[0][h][1]),
                              fmaxf(red4[0][h][2], red4[0][h][3]));
        e[h].x = __expf(sim[h].x - m); e[h].y = __expf(sim[h].y - m);
        float s = e[h].x + e[h].y;
#pragma unroll
        for (int off = 32; off; off >>= 1)
            s += __shfl_down(s, off, 64);
        if (lane == 0) red4[1][h][wave] = s;
    }
    __syncthreads();
#pragma unroll
    for (int h = 0; h < HEADS; ++h) {
        const float s = (red4[1][h][0] + red4[1][h][1]) +
                        (red4[1][h][2] + red4[1][h][3]);
        const float r = 1.f / s;
        ((float2*)&ps[h][0])[t] = make_float2(e[h].x * r, e[h].y * r);
    }
    __syncthreads();

    // ---- PV: wave h owns head h ----
    {
        const int h = wave;
        float acc[DH];
#pragma unroll
        for (int d = 0; d < DH; ++d) acc[d] = 0.f;
        const float2* psh = (const float2*)&ps[h][0];
        const __half2* v2 = (const __half2*)(rows + 2 * DIMC * N);
        for (int s = 0; s < 4; ++s) {
            const float2 p = psh[lane + 64 * s];
#pragma unroll
            for (int d = 0; d < DH; ++d) {
                const float2 vv = __half22float2(v2[(h * DH + d) * 256 + lane + 64 * s]);
                acc[d] = fmaf(p.x, vv.x, fmaf(p.y, vv.y, acc[d]));
            }
        }
        // XOR-swizzled in-wave transpose reduce (conflict-free)
        const int d = lane & 31, half = lane >> 5;
#pragma unroll
        for (int dd = 0; dd < DH; ++dd) red[h][dd][lane ^ dd] = acc[dd];
        float s = 0.f;
#pragma unroll
        for (int kk = 0; kk < 32; ++kk) s += red[h][d][(half * 32 + kk) ^ d];
        s += __shfl_down(s, 32, 64);
        if (lane < 32) attv[h * DH + d] = s;
    }
    __syncthreads();

    // ---- fused output projection: out[:, i] = w_out @ attv + b ----
    {
        const int po = t & 63;          // float2 o-pair index
        const int quarter = t >> 6;     // 4 quarters of 32 c each
        const float2* wT2 = (const float2*)w_outT;
        float2 a = {0.f, 0.f};
#pragma unroll 8
        for (int c = quarter * 32; c < quarter * 32 + 32; ++c) {
            const float2 wv = wT2[c * 64 + po];                // shared load
            const float av = attv[c];
            a.x = fmaf(wv.x, av, a.x); a.y = fmaf(wv.y, av, a.y);
        }
        ((float2*)&outred[quarter][0])[po] = a;
    }
    __syncthreads();
    if (t < DIMC) {
        out[t * N + i] = ((outred[0][t] + outred[1][t]) +
                          (outred[2][t] + outred[3][t])) + b_out[t];
    }
}

extern "C" void kernel_launch(void* const* d_in, const int* in_sizes, int n_in,
                              void* d_out, int out_size, void* d_ws, size_t ws_size,
                              hipStream_t stream) {
    const float* x         = (const float*)d_in[0];  // (1,128,512)
    const float* indicator = (const float*)d_in[1];  // (1,5,512,512)
    const float* w_qkv     = (const float*)d_in[2];  // (384,128)
    const float* w_ind     = (const float*)d_in[3];  // (256,5)
    const float* w_out     = (const float*)d_in[4];  // (128,128)
    const float* b_out     = (const float*)d_in[5];  // (128,)
    float* out = (float*)d_out;                      // (1,128,512)
    float* ws  = (float*)d_ws;

    pre_kernel<<<dim3(NROW_BLK + 1, 2), 256, 0, stream>>>(w_qkv, w_ind, x, w_out, ws);
    attn_kernel<<<N, 256, 0, stream>>>(ws, indicator, b_out, out);
}

// Round 2
// 98.377 us; speedup vs baseline: 1.0842x; 1.0842x over previous
//
#include <hip/hip_runtime.h>
#include <hip/hip_fp16.h>
#include <math.h>

#define N      512
#define DIMC   128
#define HEADS  4
#define DH     32
#define INDC   5
#define SCALE  0.1767766952966369f   // 32^-0.5

// Virtual output rows of the fused pre-GEMM: all are (row_weights) @ x
//   rows [0,384)   : qkv   (q rows 0..127, k 128..255, v 256..383)
//   rows [384,404) : Aq[(h*5+c)]  composite weight  Wq_rows . W_ind_k
//   rows [404,424) : Ak[(h*5+c)]  composite weight  Wk_rows . W_ind_q
// rows are stored FP16 (halves attn's L2-side K/V traffic; error << threshold)
#define QKV_ROWS 384
#define AQ_BASE  384
#define AK_BASE  404
#define TOT_ROWS 424
#define NROW_BLK (TOT_ROWS / 4)   // 106

// ws layout: [rows fp16: TOT_ROWS*N halves][MhS 64 f32][w_outT 16384 f32]
#define MHS_F    (TOT_ROWS * N / 2)      // float offset after fp16 rows
#define WOUTT_F  (MHS_F + 64)

// ---------------- Kernel 1: fused pre-GEMM + MhS + w_out transpose ----------------
__global__ __launch_bounds__(256) void pre_kernel(const float* __restrict__ w_qkv,
                                                  const float* __restrict__ w_ind,
                                                  const float* __restrict__ x,
                                                  const float* __restrict__ w_out,
                                                  float* __restrict__ ws) {
    const int bx = blockIdx.x;
    const int t  = threadIdx.x;
    __half* rows  = (__half*)ws;
    float* MhS    = ws + MHS_F;
    float* w_outT = ws + WOUTT_F;

    if (bx == NROW_BLK) {
        if (blockIdx.y != 0) return;
        // --- M[h,c,cc] = sum_d w_ind_q[h,d,c] * w_ind_k[h,d,cc], then symmetrize ---
        __shared__ float mraw[HEADS * INDC * INDC];
        if (t < HEADS * INDC * INDC) {
            const int h = t / 25, c = (t / 5) % 5, cc = t % 5;
            float acc = 0.f;
            for (int d = 0; d < DH; ++d)
                acc = fmaf(w_ind[(h * DH + d) * INDC + c],
                           w_ind[(DIMC + h * DH + d) * INDC + cc], acc);
            mraw[t] = acc;
        }
        __syncthreads();
        if (t < 64) {
            const int h = t >> 4, idx = t & 15;
            const int PC[10]  = {0, 0, 0, 0, 1, 1, 1, 2, 2, 3};
            const int PCC[10] = {1, 2, 3, 4, 2, 3, 4, 3, 4, 4};
            float s = 0.f;
            if (idx < 5) {
                s = mraw[h * 25 + idx * 5 + idx];
            } else if (idx < 15) {
                const int c = PC[idx - 5], cc = PCC[idx - 5];
                s = mraw[h * 25 + c * 5 + cc] + mraw[h * 25 + cc * 5 + c];
            }
            MhS[h * 16 + idx] = s;
        }
        // --- transpose w_out (128x128) so the fused outproj reads coalesced ---
        for (int idx = t; idx < DIMC * DIMC; idx += 256) {
            const int o = idx >> 7, c = idx & 127;
            w_outT[c * DIMC + o] = w_out[idx];
        }
        return;
    }

    // --- 4 virtual rows per block, c-major float4 layout in LDS ---
    __shared__ float ws2[4 * DIMC];   // ws2[c*4 + r]
    const int o0 = bx * 4;
    for (int idx = t; idx < 4 * DIMC; idx += 256) {
        const int r = idx & 3, m = idx >> 2;
        const int row = o0 + r;
        float val;
        if (row < QKV_ROWS) {
            val = w_qkv[row * DIMC + m];
        } else if (row < AK_BASE) {              // Aq composite: q-rows . W_ind_k
            const int rr = row - AQ_BASE, h = rr / INDC, c = rr % INDC;
            float acc = 0.f;
            for (int d = 0; d < DH; ++d)
                acc = fmaf(w_qkv[(h * DH + d) * DIMC + m],
                           w_ind[(DIMC + h * DH + d) * INDC + c], acc);
            val = acc;
        } else {                                  // Ak composite: k-rows . W_ind_q
            const int rr = row - AK_BASE, h = rr / INDC, c = rr % INDC;
            float acc = 0.f;
            for (int d = 0; d < DH; ++d)
                acc = fmaf(w_qkv[(DIMC + h * DH + d) * DIMC + m],
                           w_ind[(h * DH + d) * INDC + c], acc);
            val = acc;
        }
        ws2[m * 4 + r] = val;
    }
    __syncthreads();

    const int i = blockIdx.y * 256 + t;   // i-split halves per-block x traffic
    float acc[4] = {0.f, 0.f, 0.f, 0.f};
#pragma unroll 8
    for (int c = 0; c < DIMC; ++c) {
        const float xv = x[c * N + i];
        const float4 wv = *(const float4*)(ws2 + c * 4);
        acc[0] = fmaf(wv.x, xv, acc[0]);
        acc[1] = fmaf(wv.y, xv, acc[1]);
        acc[2] = fmaf(wv.z, xv, acc[2]);
        acc[3] = fmaf(wv.w, xv, acc[3]);
    }
#pragma unroll
    for (int r = 0; r < 4; ++r) rows[(o0 + r) * N + i] = __float2half(acc[r]);
}

// -- Kernel 2: per-i-pair mega kernel, WAVE-PER-HEAD pipeline --
// wave h owns head h end-to-end: sim -> shuffle-only softmax (no barriers,
// no LDS ps round trip) -> PV from registers. Barriers: 3 (was 6).
__global__ __launch_bounds__(256) void attn_kernel(const float* __restrict__ ws,
                                                   const float* __restrict__ ind,
                                                   const float* __restrict__ b_out,
                                                   float* __restrict__ out) {
    const int i0   = blockIdx.x * 2;
    const int t    = threadIdx.x;
    const int lane = t & 63;
    const int h    = t >> 6;     // wave index == head

    const __half* rows  = (const __half*)ws;
    const float* MhS    = ws + MHS_F;
    const float* w_outT = ws + WOUTT_F;

    __shared__ float qs[2][DIMC];
    __shared__ float aqs[2][HEADS * INDC];
    __shared__ float msS[HEADS * 16];
    __shared__ float red[HEADS][DH][64];    // 32 KB (reused for both i)
    __shared__ float attv[2][DIMC];
    __shared__ float outred[4][2][DIMC];    // 4 KB

    // ---- issue indicator loads (cold HBM) FIRST, before the staging barrier ----
    // lane g = lane + 64*s owns j-group [4g, 4g+3] of the full 512-j row.
    float4 ic0[2][INDC], ic1[2][INDC];
#pragma unroll
    for (int s = 0; s < 2; ++s) {
        const int g = lane + 64 * s;
#pragma unroll
        for (int c = 0; c < INDC; ++c) {
            ic0[s][c] = ((const float4*)(ind + (c * N + i0) * N))[g];
            ic1[s][c] = ((const float4*)(ind + (c * N + i0 + 1) * N))[g];
        }
    }

    // ---- stage q / aq / MhS into LDS ----
    const __half* q  = rows;
    const __half* Aq = rows + 3 * DIMC * N;
    if (t < DIMC) qs[0][t] = __half2float(q[t * N + i0]);
    else          qs[1][t - DIMC] = __half2float(q[(t - DIMC) * N + i0 + 1]);
    if (t < 2 * HEADS * INDC) {
        const int ii = t / (HEADS * INDC), r = t % (HEADS * INDC);
        aqs[ii][r] = __half2float(Aq[r * N + i0 + ii]);
    } else if (t < 2 * HEADS * INDC + 64) {
        msS[t - 2 * HEADS * INDC] = MhS[t - 2 * HEADS * INDC];
    }
    __syncthreads();

    const float2* k4  = (const float2*)(rows + DIMC * N);           // half4 rows
    const float2* v4  = (const float2*)(rows + 2 * DIMC * N);
    const float2* Ak4 = (const float2*)(rows + (3 * DIMC + HEADS * INDC) * N);

    // ---- sim: wave h, all 512 j of head h (4 j per lane per s) ----
    float4 sr0[2], sr1[2];
    float m0 = -1e30f, m1 = -1e30f;
#pragma unroll
    for (int s = 0; s < 2; ++s) {
        const int g = lane + 64 * s;
        float4 a0 = {0.f, 0.f, 0.f, 0.f}, a1 = {0.f, 0.f, 0.f, 0.f};
#pragma unroll
        for (int d = 0; d < DH; ++d) {
            const float2 raw = k4[(h * DH + d) * 128 + g];
            const float2 fa = __half22float2(*(const __half2*)&raw.x);
            const float2 fb = __half22float2(*(const __half2*)&raw.y);
            const float q0 = qs[0][h * DH + d], q1 = qs[1][h * DH + d];
            a0.x = fmaf(q0, fa.x, a0.x); a0.y = fmaf(q0, fa.y, a0.y);
            a0.z = fmaf(q0, fb.x, a0.z); a0.w = fmaf(q0, fb.y, a0.w);
            a1.x = fmaf(q1, fa.x, a1.x); a1.y = fmaf(q1, fa.y, a1.y);
            a1.z = fmaf(q1, fb.x, a1.z); a1.w = fmaf(q1, fb.y, a1.w);
        }
#pragma unroll
        for (int c = 0; c < INDC; ++c) {
            const float2 raw = Ak4[(h * INDC + c) * 128 + g];
            const float2 fa = __half22float2(*(const __half2*)&raw.x);
            const float2 fb = __half22float2(*(const __half2*)&raw.y);
            const float b0 = aqs[0][h * INDC + c], b1 = aqs[1][h * INDC + c];
            const float4 v0 = ic0[s][c], v1 = ic1[s][c];
            a0.x = fmaf(b0 + fa.x, v0.x, a0.x); a0.y = fmaf(b0 + fa.y, v0.y, a0.y);
            a0.z = fmaf(b0 + fb.x, v0.z, a0.z); a0.w = fmaf(b0 + fb.y, v0.w, a0.w);
            a1.x = fmaf(b1 + fa.x, v1.x, a1.x); a1.y = fmaf(b1 + fa.y, v1.y, a1.y);
            a1.z = fmaf(b1 + fb.x, v1.z, a1.z); a1.w = fmaf(b1 + fb.y, v1.w, a1.w);
        }
        // quadratic term: 15 symmetric (c,cc) pairs, coefficients MhS
        const int PCf[15]  = {0, 1, 2, 3, 4, 0, 0, 0, 0, 1, 1, 1, 2, 2, 3};
        const int PCCf[15] = {0, 1, 2, 3, 4, 1, 2, 3, 4, 2, 3, 4, 3, 4, 4};
#pragma unroll
        for (int p = 0; p < 15; ++p) {
            const float sv = msS[h * 16 + p];
            const float4 A0 = ic0[s][PCf[p]], B0 = ic0[s][PCCf[p]];
            const float4 A1 = ic1[s][PCf[p]], B1 = ic1[s][PCCf[p]];
            a0.x = fmaf(sv, A0.x * B0.x, a0.x); a0.y = fmaf(sv, A0.y * B0.y, a0.y);
            a0.z = fmaf(sv, A0.z * B0.z, a0.z); a0.w = fmaf(sv, A0.w * B0.w, a0.w);
            a1.x = fmaf(sv, A1.x * B1.x, a1.x); a1.y = fmaf(sv, A1.y * B1.y, a1.y);
            a1.z = fmaf(sv, A1.z * B1.z, a1.z); a1.w = fmaf(sv, A1.w * B1.w, a1.w);
        }
        sr0[s] = make_float4(SCALE * a0.x, SCALE * a0.y, SCALE * a0.z, SCALE * a0.w);
        sr1[s] = make_float4(SCALE * a1.x, SCALE * a1.y, SCALE * a1.z, SCALE * a1.w);
        m0 = fmaxf(m0, fmaxf(fmaxf(sr0[s].x, sr0[s].y), fmaxf(sr0[s].z, sr0[s].w)));
        m1 = fmaxf(m1, fmaxf(fmaxf(sr1[s].x, sr1[s].y), fmaxf(sr1[s].z, sr1[s].w)));
    }

    // ---- softmax: pure in-wave butterflies, no barriers ----
#pragma unroll
    for (int off = 1; off < 64; off <<= 1) {
        m0 = fmaxf(m0, __shfl_xor(m0, off, 64));
        m1 = fmaxf(m1, __shfl_xor(m1, off, 64));
    }
    float4 e0[2], e1[2];
    float sum0 = 0.f, sum1 = 0.f;
#pragma unroll
    for (int s = 0; s < 2; ++s) {
        e0[s].x = __expf(sr0[s].x - m0); e0[s].y = __expf(sr0[s].y - m0);
        e0[s].z = __expf(sr0[s].z - m0); e0[s].w = __expf(sr0[s].w - m0);
        e1[s].x = __expf(sr1[s].x - m1); e1[s].y = __expf(sr1[s].y - m1);
        e1[s].z = __expf(sr1[s].z - m1); e1[s].w = __expf(sr1[s].w - m1);
        sum0 += (e0[s].x + e0[s].y) + (e0[s].z + e0[s].w);
        sum1 += (e1[s].x + e1[s].y) + (e1[s].z + e1[s].w);
    }
#pragma unroll
    for (int off = 1; off < 64; off <<= 1) {
        sum0 += __shfl_xor(sum0, off, 64);
        sum1 += __shfl_xor(sum1, off, 64);
    }
    const float r0 = 1.f / sum0, r1 = 1.f / sum1;   // folded into attv store

    // ---- PV: unnormalized P (registers) x V, wave-local ----
    float acc0[DH], acc1[DH];
#pragma unroll
    for (int d = 0; d < DH; ++d) { acc0[d] = 0.f; acc1[d] = 0.f; }
#pragma unroll
    for (int s = 0; s < 2; ++s) {
        const int g = lane + 64 * s;
        const float4 p0 = e0[s], p1 = e1[s];
#pragma unroll
        for (int d = 0; d < DH; ++d) {
            const float2 raw = v4[(h * DH + d) * 128 + g];
            const float2 fa = __half22float2(*(const __half2*)&raw.x);
            const float2 fb = __half22float2(*(const __half2*)&raw.y);
            acc0[d] = fmaf(p0.x, fa.x, fmaf(p0.y, fa.y,
                      fmaf(p0.z, fb.x, fmaf(p0.w, fb.y, acc0[d]))));
            acc1[d] = fmaf(p1.x, fa.x, fmaf(p1.y, fa.y,
                      fmaf(p1.z, fb.x, fmaf(p1.w, fb.y, acc1[d]))));
        }
    }

    // ---- XOR-swizzled in-wave transpose reduce (conflict-free), i0 then i1 ----
    {
        const int d = lane & 31, half = lane >> 5;
#pragma unroll
        for (int dd = 0; dd < DH; ++dd) red[h][dd][lane ^ dd] = acc0[dd];
        float s = 0.f;
#pragma unroll
        for (int kk = 0; kk < 32; ++kk) s += red[h][d][(half * 32 + kk) ^ d];
        s += __shfl_down(s, 32, 64);
        if (lane < 32) attv[0][h * DH + d] = s * r0;
#pragma unroll
        for (int dd = 0; dd < DH; ++dd) red[h][dd][lane ^ dd] = acc1[dd];
        s = 0.f;
#pragma unroll
        for (int kk = 0; kk < 32; ++kk) s += red[h][d][(half * 32 + kk) ^ d];
        s += __shfl_down(s, 32, 64);
        if (lane < 32) attv[1][h * DH + d] = s * r1;
    }
    __syncthreads();

    // ---- fused output projection: out[:, i0+ii] = w_out @ attv[ii] + b ----
    {
        const int po = t & 63;          // float2 o-pair index
        const int quarter = t >> 6;     // 4 quarters of 32 c each
        const float2* wT2 = (const float2*)w_outT;
        float2 a0 = {0.f, 0.f}, a1 = {0.f, 0.f};
#pragma unroll 8
        for (int c = quarter * 32; c < quarter * 32 + 32; ++c) {
            const float2 wv = wT2[c * 64 + po];                // shared load
            const float av0 = attv[0][c], av1 = attv[1][c];
            a0.x = fmaf(wv.x, av0, a0.x); a0.y = fmaf(wv.y, av0, a0.y);
            a1.x = fmaf(wv.x, av1, a1.x); a1.y = fmaf(wv.y, av1, a1.y);
        }
        ((float2*)&outred[quarter][0][0])[po] = a0;
        ((float2*)&outred[quarter][1][0])[po] = a1;
    }
    __syncthreads();
    {
        const int o = t & 127, ii = t >> 7;
        out[o * N + i0 + ii] = ((outred[0][ii][o] + outred[1][ii][o]) +
                                (outred[2][ii][o] + outred[3][ii][o])) + b_out[o];
    }
}

extern "C" void kernel_launch(void* const* d_in, const int* in_sizes, int n_in,
                              void* d_out, int out_size, void* d_ws, size_t ws_size,
                              hipStream_t stream) {
    const float* x         = (const float*)d_in[0];  // (1,128,512)
    const float* indicator = (const float*)d_in[1];  // (1,5,512,512)
    const float* w_qkv     = (const float*)d_in[2];  // (384,128)
    const float* w_ind     = (const float*)d_in[3];  // (256,5)
    const float* w_out     = (const float*)d_in[4];  // (128,128)
    const float* b_out     = (const float*)d_in[5];  // (128,)
    float* out = (float*)d_out;                      // (1,128,512)
    float* ws  = (float*)d_ws;

    pre_kernel<<<dim3(NROW_BLK + 1, 2), 256, 0, stream>>>(w_qkv, w_ind, x, w_out, ws);
    attn_kernel<<<N / 2, 256, 0, stream>>>(ws, indicator, b_out, out);
}